// Round 7
// baseline (91.134 us; speedup 1.0000x reference)
//
#include <hip/hip_runtime.h>
#include <hip/hip_bf16.h>

// Problem constants (B,T,C,H) = (4, 2048, 1024, 64)
#define B_ 4
#define T_ 2048
#define C_ 1024
#define H_ 64
#define M_ (B_ * T_)   // 8192 rows

// Split-K attention geometry: q-tile = 16 rows, k-tile = 64 keys,
// chunk = 4 k-tiles = 256 keys. Units per batch:
//   nch(qt) = qt/16 + 1;  sum over qt=0..127 = 576.
#define UPB 576
#define NUNITS (UPB * B_)   // 2304

typedef __attribute__((ext_vector_type(8))) short short8v;  // 8 bf16 = 4 VGPRs
typedef __attribute__((ext_vector_type(4))) float f32x4;

static __device__ __forceinline__ short bf16_bits(float f) {
    return __builtin_bit_cast(short, __float2bfloat16(f));
}

// ---------------------------------------------------------------------------
// Kernel 0: transpose+convert weights.  W[c][h] fp32 -> wt[m][h][c] bf16.
// ---------------------------------------------------------------------------
__global__ __launch_bounds__(256) void w_transpose(
    const float* __restrict__ Wq,
    const float* __restrict__ Wk,
    const float* __restrict__ Wv,
    ushort* __restrict__ wt)
{
    const int idx = blockIdx.x * 256 + threadIdx.x;        // 0 .. 3*64*256-1
    const int m  = idx / (H_ * (C_ / 4));
    const int r  = idx % (H_ * (C_ / 4));
    const int h  = r / (C_ / 4);
    const int c0 = (r % (C_ / 4)) * 4;
    const float* W = (m == 0) ? Wq : (m == 1) ? Wk : Wv;
    ushort4 o;
    o.x = (ushort)bf16_bits(W[(size_t)(c0 + 0) * H_ + h]);
    o.y = (ushort)bf16_bits(W[(size_t)(c0 + 1) * H_ + h]);
    o.z = (ushort)bf16_bits(W[(size_t)(c0 + 2) * H_ + h]);
    o.w = (ushort)bf16_bits(W[(size_t)(c0 + 3) * H_ + h]);
    *reinterpret_cast<ushort4*>(&wt[((size_t)m * H_ + h) * C_ + c0]) = o;
}

// ---------------------------------------------------------------------------
// Kernel 1: fused QKV projection via bf16 MFMA.
// Depth-4 register pipeline (fully unrolled => static slot indices): 5 load
// streams x 4 slots = up to 20 loads in flight. launch_bounds(256,1): grid
// is 2 blocks/CU (occupancy grid-limited), so VGPRs are free — spend them.
// mfma_f32_16x16x32_bf16 mapping (verified):
//   A: row=lane&15, k=(lane>>4)*8+i   B: col=lane&15, k=(lane>>4)*8+i
//   D: col=lane&15, row=(lane>>4)*4+reg
// ---------------------------------------------------------------------------
__global__ __launch_bounds__(256, 1) void qkv_mfma(
    const float* __restrict__ x,
    const ushort* __restrict__ wt,     // [3][H][C] bf16 bits
    ushort* __restrict__ qb,
    ushort* __restrict__ kb,
    ushort* __restrict__ vtp)
{
    __shared__ ushort q_s[16][72];     // [t][h], padded
    __shared__ ushort k_s[16][72];
    __shared__ ushort v_s[64][24];     // [h][t], padded (transposed V tile)

    const int lane = threadIdx.x & 63;
    const int wid  = threadIdx.x >> 6;
    const int row0 = blockIdx.x * 16;
    const int col0 = wid * 16;
    const int l15  = lane & 15;
    const int kg   = lane >> 4;

    const float*  xp = x  + (size_t)(row0 + l15) * C_ + kg * 8;
    const ushort* bq = wt + (size_t)(0 * H_ + col0 + l15) * C_ + kg * 8;
    const ushort* bk = bq + (size_t)H_ * C_;
    const ushort* bv = bk + (size_t)H_ * C_;

    f32x4 accq = {0.f, 0.f, 0.f, 0.f};
    f32x4 acck = {0.f, 0.f, 0.f, 0.f};
    f32x4 accv = {0.f, 0.f, 0.f, 0.f};

    // ---- depth-4 register pipeline ----
    f32x4  A0[4], A1[4];
    short8v FQ[4], FK[4], FV[4];
    #pragma unroll
    for (int i = 0; i < 4; ++i) {
        A0[i] = *reinterpret_cast<const f32x4*>(xp + i * 32);
        A1[i] = *reinterpret_cast<const f32x4*>(xp + i * 32 + 4);
        FQ[i] = *reinterpret_cast<const short8v*>(bq + i * 32);
        FK[i] = *reinterpret_cast<const short8v*>(bk + i * 32);
        FV[i] = *reinterpret_cast<const short8v*>(bv + i * 32);
    }

    #pragma unroll
    for (int kk = 0; kk < C_ / 32; ++kk) {
        const int sl = kk & 3;                 // constant after full unroll
        short8v af;
        af[0] = bf16_bits(A0[sl][0]); af[1] = bf16_bits(A0[sl][1]);
        af[2] = bf16_bits(A0[sl][2]); af[3] = bf16_bits(A0[sl][3]);
        af[4] = bf16_bits(A1[sl][0]); af[5] = bf16_bits(A1[sl][1]);
        af[6] = bf16_bits(A1[sl][2]); af[7] = bf16_bits(A1[sl][3]);

        accq = __builtin_amdgcn_mfma_f32_16x16x32_bf16(af, FQ[sl], accq, 0, 0, 0);
        acck = __builtin_amdgcn_mfma_f32_16x16x32_bf16(af, FK[sl], acck, 0, 0, 0);
        accv = __builtin_amdgcn_mfma_f32_16x16x32_bf16(af, FV[sl], accv, 0, 0, 0);

        if (kk + 4 < C_ / 32) {
            A0[sl] = *reinterpret_cast<const f32x4*>(xp + (kk + 4) * 32);
            A1[sl] = *reinterpret_cast<const f32x4*>(xp + (kk + 4) * 32 + 4);
            FQ[sl] = *reinterpret_cast<const short8v*>(bq + (kk + 4) * 32);
            FK[sl] = *reinterpret_cast<const short8v*>(bk + (kk + 4) * 32);
            FV[sl] = *reinterpret_cast<const short8v*>(bv + (kk + 4) * 32);
        }
    }

    const float qscale = 0.03125f;  // 1024^-0.5
    #pragma unroll
    for (int j = 0; j < 4; ++j) {
        const int tr = kg * 4 + j;                 // row within 16-row tile
        q_s[tr][col0 + l15] = (ushort)bf16_bits(accq[j] * qscale);
        k_s[tr][col0 + l15] = (ushort)bf16_bits(acck[j]);
        v_s[col0 + l15][tr] = (ushort)bf16_bits(accv[j]);
    }
    __syncthreads();

    // q/k: 16 rows x 64 h; thread (row = tid>>4, seg = tid&15) -> ushort4.
    {
        const int row = threadIdx.x >> 4;
        const int seg = threadIdx.x & 15;
        const size_t o = (size_t)(row0 + row) * H_ + seg * 4;
        *reinterpret_cast<ushort4*>(&qb[o]) =
            *reinterpret_cast<const ushort4*>(&q_s[row][seg * 4]);
        *reinterpret_cast<ushort4*>(&kb[o]) =
            *reinterpret_cast<const ushort4*>(&k_s[row][seg * 4]);
    }
    // vtp: 64 h x 16 t; thread (h = tid>>2, seg = tid&3) -> ushort4.
    {
        const int h   = threadIdx.x >> 2;
        const int seg = threadIdx.x & 3;
        const int bb  = row0 >> 11;
        const int tt0 = row0 & (T_ - 1);
        *reinterpret_cast<ushort4*>(&vtp[((size_t)bb * H_ + h) * T_ + tt0 + seg * 4]) =
            *reinterpret_cast<const ushort4*>(&v_s[h][seg * 4]);
    }
}

// ---------------------------------------------------------------------------
// Kernel 2a: split-K causal flash attention partials via bf16 MFMA.
// Grid 576 blocks x 256 thr (4 waves); wave = one unit (b, qt, chunk).
// 2-stage K pipeline: K[kt+1] prefetched during softmax/PV of kt; V[kt]
// issued at tile top (QK MFMAs + softmax cover its latency). Loop over <=4
// tiles fully unrolled with wave-uniform break -> static register indices.
// ---------------------------------------------------------------------------
__global__ __launch_bounds__(256, 1) void attn_part(
    const ushort* __restrict__ qb,
    const ushort* __restrict__ kb,
    const ushort* __restrict__ vtp,
    float* __restrict__ pO,       // [NUNITS][16][64]
    float* __restrict__ pML)      // [NUNITS][32]  (m rows 0-15, l rows 16-31)
{
    __shared__ ushort p_lds[4][16][68];   // per-wave P tile

    const int wid  = threadIdx.x >> 6;
    const int lane = threadIdx.x & 63;
    const int l15  = lane & 15;
    const int g    = lane >> 4;

    const int unit = blockIdx.x * 4 + wid;
    const int b = unit / UPB;
    const int u = unit - b * UPB;
    int a = 0;
    #pragma unroll
    for (int t = 1; t < 8; ++t)
        if (u >= 8 * t * (t + 1)) a = t;
    const int u2    = u - 8 * a * (a + 1);
    const int rr    = u2 / (a + 1);
    const int chunk = u2 - rr * (a + 1);
    const int qt    = a * 16 + rr;

    const int qrow0   = qt * 16;
    const int diag_kt = qt >> 2;
    const int kt_lo   = chunk * 4;
    const int kt_hi   = min(kt_lo + 4, diag_kt + 1);   // exclusive
    const int ntiles  = kt_hi - kt_lo;                 // 1..4, wave-uniform

    const ushort* kbase_b = kb  + (size_t)b * T_ * H_;
    const ushort* vbase_b = vtp + (size_t)b * H_ * T_;

    const ushort* qp = qb + ((size_t)(b * T_ + qrow0 + l15)) * H_ + g * 8;
    const short8v qf0 = *reinterpret_cast<const short8v*>(qp);
    const short8v qf1 = *reinterpret_cast<const short8v*>(qp + 32);

#define LOAD_K(KT, F0, F1)                                                    \
    {                                                                         \
        const ushort* kbase_ = kbase_b + (size_t)(KT) * 64 * H_;              \
        _Pragma("unroll")                                                     \
        for (int c = 0; c < 4; ++c) {                                         \
            const ushort* kp_ = kbase_ + (size_t)(c * 16 + l15) * H_ + g * 8; \
            F0[c] = *reinterpret_cast<const short8v*>(kp_);                   \
            F1[c] = *reinterpret_cast<const short8v*>(kp_ + 32);              \
        }                                                                     \
    }

    f32x4 accO[4];
    float m[4], l[4];
    #pragma unroll
    for (int r = 0; r < 4; ++r) {
        accO[r] = (f32x4){0.f, 0.f, 0.f, 0.f};
        m[r] = -1e30f; l[r] = 0.f;
    }

    short8v kcur0[4], kcur1[4];
    short8v knxt0[4], knxt1[4];
    LOAD_K(kt_lo, kcur0, kcur1);

    #pragma unroll 4
    for (int i = 0; i < 4; ++i) {
        if (i >= ntiles) break;                 // wave-uniform
        const int kt = kt_lo + i;
        const int k0 = kt * 64;
        const bool mask = (kt == diag_kt);

        // ---- V fragment loads for this tile (latency hidden by QK+softmax)
        short8v vf0[4], vf1[4];
        #pragma unroll
        for (int ht = 0; ht < 4; ++ht) {
            const ushort* vp = vbase_b + (size_t)(ht * 16 + l15) * T_ + k0 + g * 8;
            vf0[ht] = *reinterpret_cast<const short8v*>(vp);
            vf1[ht] = *reinterpret_cast<const short8v*>(vp + 32);
        }

        // ---- prefetch next K tile (latency hidden by softmax+PV) ----
        const int ktn = (i + 1 < ntiles) ? kt + 1 : kt;
        LOAD_K(ktn, knxt0, knxt1);

        // ---- QK^T: S[16 q x 64 keys] as 4 col-tiles (kcur ready) ----
        f32x4 s[4];
        #pragma unroll
        for (int c = 0; c < 4; ++c) {
            s[c] = (f32x4){0.f, 0.f, 0.f, 0.f};
            s[c] = __builtin_amdgcn_mfma_f32_16x16x32_bf16(qf0, kcur0[c], s[c], 0, 0, 0);
            s[c] = __builtin_amdgcn_mfma_f32_16x16x32_bf16(qf1, kcur1[c], s[c], 0, 0, 0);
        }

        // ---- causal mask (diagonal tile only) ----
        if (mask) {
            #pragma unroll
            for (int c = 0; c < 4; ++c) {
                const int key = k0 + c * 16 + l15;
                #pragma unroll
                for (int r = 0; r < 4; ++r) {
                    const int row = qrow0 + g * 4 + r;
                    if (key > row) s[c][r] = -1e30f;
                }
            }
        }

        // ---- online softmax: per-row reduce across 16 lanes ----
        float tm[4];
        #pragma unroll
        for (int r = 0; r < 4; ++r) {
            tm[r] = fmaxf(fmaxf(s[0][r], s[1][r]), fmaxf(s[2][r], s[3][r]));
            #pragma unroll
            for (int off = 1; off < 16; off <<= 1)
                tm[r] = fmaxf(tm[r], __shfl_xor(tm[r], off));
        }
        float corr[4];
        #pragma unroll
        for (int r = 0; r < 4; ++r) {
            const float mn = fmaxf(m[r], tm[r]);
            corr[r] = __expf(m[r] - mn);
            m[r] = mn;
        }
        #pragma unroll
        for (int ht = 0; ht < 4; ++ht)
            #pragma unroll
            for (int r = 0; r < 4; ++r)
                accO[ht][r] *= corr[r];

        float ts[4] = {0.f, 0.f, 0.f, 0.f};
        #pragma unroll
        for (int c = 0; c < 4; ++c) {
            #pragma unroll
            for (int r = 0; r < 4; ++r) {
                const float p = __expf(s[c][r] - m[r]);
                ts[r] += p;
                p_lds[wid][g * 4 + r][c * 16 + l15] = (ushort)bf16_bits(p);
            }
        }
        #pragma unroll
        for (int r = 0; r < 4; ++r) {
            #pragma unroll
            for (int off = 1; off < 16; off <<= 1)
                ts[r] += __shfl_xor(ts[r], off);
            l[r] = l[r] * corr[r] + ts[r];
        }

        // ---- PA fragments from per-wave LDS tile ----
        const short8v pa0 = *reinterpret_cast<const short8v*>(&p_lds[wid][l15][g * 8]);
        const short8v pa1 = *reinterpret_cast<const short8v*>(&p_lds[wid][l15][32 + g * 8]);

        // ---- PV: O += P x V ----
        #pragma unroll
        for (int ht = 0; ht < 4; ++ht) {
            accO[ht] = __builtin_amdgcn_mfma_f32_16x16x32_bf16(pa0, vf0[ht], accO[ht], 0, 0, 0);
            accO[ht] = __builtin_amdgcn_mfma_f32_16x16x32_bf16(pa1, vf1[ht], accO[ht], 0, 0, 0);
        }

        // ---- rotate K pipeline (SSA-renamed away by full unroll) ----
        #pragma unroll
        for (int c = 0; c < 4; ++c) { kcur0[c] = knxt0[c]; kcur1[c] = knxt1[c]; }
    }
#undef LOAD_K

    // ---- partial store ----
    float* po = pO + (size_t)unit * (16 * 64);
    #pragma unroll
    for (int ht = 0; ht < 4; ++ht)
        #pragma unroll
        for (int r = 0; r < 4; ++r)
            po[(g * 4 + r) * 64 + ht * 16 + l15] = accO[ht][r];
    if (l15 == 0) {
        #pragma unroll
        for (int r = 0; r < 4; ++r) {
            pML[(size_t)unit * 32 + (g * 4 + r)]      = m[r];
            pML[(size_t)unit * 32 + 16 + (g * 4 + r)] = l[r];
        }
    }
}

// ---------------------------------------------------------------------------
// Kernel 2b: merge partials.  Grid 512 blocks (b = bid>>7, qt = bid&127),
// 256 thr; thread handles (row stripe, h).  out = sum_u w_u*O_u / sum_u w_u*l_u.
// ---------------------------------------------------------------------------
__global__ __launch_bounds__(256) void attn_merge(
    const float* __restrict__ pO,
    const float* __restrict__ pML,
    float* __restrict__ out)
{
    const int b  = blockIdx.x >> 7;
    const int qt = blockIdx.x & 127;
    const int a  = qt >> 4;
    const int rr = qt & 15;
    const int base = b * UPB + 8 * a * (a + 1) + rr * (a + 1);
    const int nch  = a + 1;

    const int h  = threadIdx.x & 63;
    const int r0 = threadIdx.x >> 6;      // 0..3

    #pragma unroll
    for (int i = 0; i < 4; ++i) {
        const int row = r0 * 4 + i;       // 0..15
        float M = -1e30f;
        for (int u = 0; u < nch; ++u)
            M = fmaxf(M, pML[(size_t)(base + u) * 32 + row]);
        float O = 0.f, L = 0.f;
        for (int u = 0; u < nch; ++u) {
            const float w = __expf(pML[(size_t)(base + u) * 32 + row] - M);
            O += w * pO[(size_t)(base + u) * (16 * 64) + row * 64 + h];
            L += w * pML[(size_t)(base + u) * 32 + 16 + row];
        }
        out[((size_t)(b * T_ + qt * 16 + row)) * H_ + h] = O / L;
    }
}

// ---------------------------------------------------------------------------
// Launch. Input order is setup_inputs() dict order: x, Wk, Wq, Wv.
// ws: qb 1MB | kb 1MB | vtp 1MB | wt 384KB | pO 9.4MB | pML 294KB  (~13.1MB).
// ---------------------------------------------------------------------------
extern "C" void kernel_launch(void* const* d_in, const int* in_sizes, int n_in,
                              void* d_out, int out_size, void* d_ws, size_t ws_size,
                              hipStream_t stream)
{
    const float* x  = (const float*)d_in[0];
    const float* Wk = (const float*)d_in[1];
    const float* Wq = (const float*)d_in[2];
    const float* Wv = (const float*)d_in[3];
    float* out = (float*)d_out;

    ushort* qbp = (ushort*)d_ws;                    // [M][64]
    ushort* kbp = qbp + (size_t)M_ * H_;            // [M][64]
    ushort* vtp = kbp + (size_t)M_ * H_;            // [B][64][T]
    ushort* wt  = vtp + (size_t)B_ * H_ * T_;       // [3][64][1024]
    float*  pO  = (float*)(wt + (size_t)3 * H_ * C_);      // [NUNITS][16][64]
    float*  pML = pO + (size_t)NUNITS * 16 * 64;           // [NUNITS][32]

    w_transpose<<<dim3((3 * H_ * (C_ / 4)) / 256), dim3(256), 0, stream>>>(Wq, Wk, Wv, wt);
    qkv_mfma<<<dim3(M_ / 16), dim3(256), 0, stream>>>(x, wt, qbp, kbp, vtp);
    attn_part<<<dim3(NUNITS / 4), dim3(256), 0, stream>>>(qbp, kbp, vtp, pO, pML);
    attn_merge<<<dim3(128 * B_), dim3(256), 0, stream>>>(pO, pML, out);
}